// Round 3
// baseline (229.989 us; speedup 1.0000x reference)
//
#include <hip/hip_runtime.h>
#include <hip/hip_bf16.h>

#define T_DIM 4096
#define B_DIM 32
#define H_DIM 128
#define M_DIM (T_DIM * B_DIM)        // 131072 GEMM rows (t*B + b)
#define G_DIM 512                    // 4*H gate columns
#define TBH   ((long)M_DIM * H_DIM)  // 16777216 output elements for `outputs`

typedef __attribute__((ext_vector_type(8))) short short8;    // 8 bf16 = 4 VGPRs (MFMA A/B frag)
typedef __attribute__((ext_vector_type(4))) short short4v;   // 4 bf16 = 8 bytes
typedef __attribute__((ext_vector_type(4))) float floatx4;   // MFMA C/D frag

__device__ __forceinline__ unsigned short f2bf_rne(float x) {
    union { float f; unsigned int u; } v; v.f = x;
    unsigned int r = v.u + 0x7FFFu + ((v.u >> 16) & 1u);   // round-nearest-even
    return (unsigned short)(r >> 16);
}
__device__ __forceinline__ unsigned short f2bf_rh(float x) {
    union { float f; unsigned int u; } v; v.f = x;
    return (unsigned short)((v.u + 0x8000u) >> 16);        // round-half-up (cheap, ~unbiased)
}
__device__ __forceinline__ float sigm(float x) {
    return __builtin_amdgcn_rcpf(1.0f + __expf(-x));       // saturates cleanly at 0/1
}
__device__ __forceinline__ float tanh_fast(float x) {
    float e = __expf(-2.0f * __builtin_fabsf(x));          // in (0,1]
    float t = (1.0f - e) * __builtin_amdgcn_rcpf(1.0f + e);
    return __builtin_copysignf(t, x);
}

// blocks 0..31:  hh[b][g] = h0[b,:]·W_hh[g,:] + b_ih[g] + b_hh[g]   (fp32, 32x512)
// blocks 32..95: W_ih fp32 -> bf16 (RNE) into ws
__global__ void prep(const float* __restrict__ h0,
                     const float* __restrict__ W_hh,
                     const float* __restrict__ b_ih,
                     const float* __restrict__ b_hh,
                     const float* __restrict__ W_ih,
                     unsigned short* __restrict__ Wb,
                     float* __restrict__ hh) {
    const int tid = threadIdx.x;
    if (blockIdx.x < 32) {
        __shared__ float h0s[128];
        const int b = blockIdx.x;
        if (tid < 128) h0s[tid] = h0[b * 128 + tid];
        __syncthreads();
        for (int g = tid; g < G_DIM; g += 256) {
            float acc = b_ih[g] + b_hh[g];
            const float* wr = W_hh + g * 128;
            #pragma unroll 8
            for (int k = 0; k < 128; ++k) acc += wr[k] * h0s[k];
            hh[b * G_DIM + g] = acc;
        }
    } else {
        const int e = ((blockIdx.x - 32) * 256 + tid) * 4;   // 64*256*4 = 65536 elements
        float4 f = *(const float4*)(W_ih + e);
        short4v s;
        s[0] = (short)f2bf_rne(f.x); s[1] = (short)f2bf_rne(f.y);
        s[2] = (short)f2bf_rne(f.z); s[3] = (short)f2bf_rne(f.w);
        *(short4v*)(Wb + e) = s;
    }
}

__device__ __forceinline__ short8 cvt_frag(const float* p) {
    // 8 consecutive fp32 -> bf16x8 fragment (round-half-up)
    float4 f0 = *(const float4*)(p);
    float4 f1 = *(const float4*)(p + 4);
    short8 a;
    a[0] = (short)f2bf_rh(f0.x); a[1] = (short)f2bf_rh(f0.y);
    a[2] = (short)f2bf_rh(f0.z); a[3] = (short)f2bf_rh(f0.w);
    a[4] = (short)f2bf_rh(f1.x); a[5] = (short)f2bf_rh(f1.y);
    a[6] = (short)f2bf_rh(f1.z); a[7] = (short)f2bf_rh(f1.w);
    return a;
}

// Per block: 32 rows x 512 gate cols GEMM (K=128) + fused LSTM-cell epilogue.
// Wave w owns h-cols [w*32, w*32+32) across all 4 gates -> epilogue is wave-local.
__global__ __launch_bounds__(256, 3) void lstm_main(
    const float* __restrict__ X,              // [M,128] fp32 input rows
    const unsigned short* __restrict__ W,     // [512,128] bf16 W_ih (pre-converted, B^T layout)
    const float* __restrict__ hh,             // [32,512] fp32 precomputed
    const float* __restrict__ c0,             // [32,128] fp32
    const float* __restrict__ noise,          // [32,128] fp32
    float* __restrict__ out)                  // fp32: outputs[M*128], h_last[4096], c_last[4096]
{
    const int tid  = threadIdx.x;
    const int w    = tid >> 6;       // wave 0..3
    const int lane = tid & 63;
    const int q    = lane >> 4;      // quad 0..3
    const int lr   = lane & 15;
    const int m_base = blockIdx.x << 5;   // 32 rows per block, 32-aligned

    // Accumulators seeded with hh (fuses recurrent term + biases); b = row & 31.
    floatx4 acc[2][8];
    #pragma unroll
    for (int mt = 0; mt < 2; ++mt)
        #pragma unroll
        for (int gt = 0; gt < 4; ++gt)
            #pragma unroll
            for (int hc = 0; hc < 2; ++hc) {
                const int col = gt * 128 + w * 32 + hc * 16 + lr;
                floatx4 a;
                #pragma unroll
                for (int r = 0; r < 4; ++r)
                    a[r] = hh[((mt * 16 + q * 4 + r) & 31) * G_DIM + col];
                acc[mt][gt * 2 + hc] = a;
            }

    // GEMM: gates[m,col] += X[m,:]·W[col,:]
    const float* xr0 = X + (long)(m_base +      lr) * 128;
    const float* xr1 = X + (long)(m_base + 16 + lr) * 128;
    #pragma unroll
    for (int kt = 0; kt < 4; ++kt) {
        // A frag: lane holds A[m = mt*16+lr][k = kt*32 + q*8 + 0..8), cvt fp32->bf16
        short8 a0 = cvt_frag(xr0 + kt * 32 + q * 8);
        short8 a1 = cvt_frag(xr1 + kt * 32 + q * 8);
        #pragma unroll
        for (int gt = 0; gt < 4; ++gt)
            #pragma unroll
            for (int hc = 0; hc < 2; ++hc) {
                const int col = gt * 128 + w * 32 + hc * 16 + lr;
                // B frag: lane holds B[k = kt*32 + q*8 + 0..8)][n = lr] = W[col][k]
                short8 bf = *(const short8*)(W + col * 128 + kt * 32 + q * 8);
                const int n = gt * 2 + hc;
                acc[0][n] = __builtin_amdgcn_mfma_f32_16x16x32_bf16(a0, bf, acc[0][n], 0, 0, 0);
                acc[1][n] = __builtin_amdgcn_mfma_f32_16x16x32_bf16(a1, bf, acc[1][n], 0, 0, 0);
            }
    }

    // Epilogue: C/D layout col = lane&15, row = (lane>>4)*4 + reg
    const bool last = (m_base == M_DIM - 32);   // whole last block is t = T-1
    #pragma unroll
    for (int mt = 0; mt < 2; ++mt)
        #pragma unroll
        for (int r = 0; r < 4; ++r) {
            const int row = m_base + mt * 16 + q * 4 + r;
            const int b   = row & 31;
            #pragma unroll
            for (int hc = 0; hc < 2; ++hc) {
                const int hcol = w * 32 + hc * 16 + lr;
                const float gi = sigm(acc[mt][0 + hc][r]);
                const float gf = sigm(acc[mt][2 + hc][r]);
                const float gg = tanh_fast(acc[mt][4 + hc][r]);
                const float go = sigm(acc[mt][6 + hc][r]);
                const float cc = gf * c0[b * 128 + hcol] + gi * gg;
                const float hv = go * tanh_fast(cc) + noise[b * 128 + hcol];
                out[(long)row * 128 + hcol] = hv;
                if (last) {
                    out[TBH +        b * 128 + hcol] = hv;
                    out[TBH + 4096 + b * 128 + hcol] = cc;
                }
            }
        }
}

extern "C" void kernel_launch(void* const* d_in, const int* in_sizes, int n_in,
                              void* d_out, int out_size, void* d_ws, size_t ws_size,
                              hipStream_t stream) {
    const float* X     = (const float*)d_in[0];
    const float* h0    = (const float*)d_in[1];
    const float* c0    = (const float*)d_in[2];
    const float* noise = (const float*)d_in[3];
    const float* W_ih  = (const float*)d_in[4];
    const float* W_hh  = (const float*)d_in[5];
    const float* b_ih  = (const float*)d_in[6];
    const float* b_hh  = (const float*)d_in[7];

    unsigned short* Wb = (unsigned short*)d_ws;              // [512*128] bf16 = 128 KB
    float* hh = (float*)((char*)d_ws + 512 * 128 * sizeof(unsigned short));  // 64 KB
    float* out = (float*)d_out;

    prep<<<dim3(96), dim3(256), 0, stream>>>(h0, W_hh, b_ih, b_hh, W_ih, Wb, hh);
    lstm_main<<<dim3(M_DIM / 32), dim3(256), 0, stream>>>(X, Wb, hh, c0, noise, out);
}